// Round 12
// baseline (367.644 us; speedup 1.0000x reference)
//
#include <hip/hip_runtime.h>

#define NEG_SLOPE 0.2f
#define CAP 64  // bucket capacity per node; overflow handled exactly

using f32x4 = __attribute__((ext_vector_type(4))) float;
using bf16x8 = __attribute__((ext_vector_type(8))) short;

__device__ inline unsigned short bf16_rne(float f) {
    unsigned int u = __float_as_uint(f);
    return (unsigned short)((u + 0x7FFF + ((u >> 16) & 1)) >> 16);
}
__device__ inline float bf16_tof(unsigned short h) {
    return __uint_as_float(((unsigned int)h) << 16);
}

// ---------------------------------------------------------------------------
// prep: wprep (first 24 blocks) + zero cnt/ovf (rest).
// ---------------------------------------------------------------------------
__global__ void prep_kernel(const float* __restrict__ W0,
                            const float* __restrict__ W1,
                            const float* __restrict__ W2,
                            unsigned short* __restrict__ wf,
                            int* __restrict__ cnt, int nz) {
    if (blockIdx.x < 24) {
        int tid = blockIdx.x * 256 + threadIdx.x;
        if (tid >= 3 * 2048) return;
        int layer = tid >> 11;
        int rem = tid & 2047;
        int kstep = rem >> 9;
        int ct = (rem >> 6) & 7;
        int lane = rem & 63;
        const float* W = (layer == 0) ? W0 : (layer == 1) ? W1 : W2;
        unsigned short* hi = wf + (size_t)layer * 32768 +
                             ((size_t)(kstep * 8 + ct) * 64 + lane) * 8;
        unsigned short* lo = hi + 16384;
#pragma unroll
        for (int j = 0; j < 8; ++j) {
            int k = kstep * 32 + (lane >> 4) * 8 + j;
            int n = ct * 16 + (lane & 15);
            float f = W[k * 128 + n];
            unsigned short h = bf16_rne(f);
            hi[j] = h;
            lo[j] = bf16_rne(f - bf16_tof(h));
        }
    } else {
        int i = (blockIdx.x - 24) * 256 + threadIdx.x;
        if (i < nz) cnt[i] = 0;
    }
}

// ---------------------------------------------------------------------------
__device__ inline void build_body(int i, const void* __restrict__ ei_raw,
                                  int E, int* __restrict__ cnt,
                                  int* __restrict__ bucket,
                                  int* __restrict__ ovf_src,
                                  int* __restrict__ ovf_dst,
                                  int* __restrict__ ovf_cnt) {
    const int* as32 = (const int*)ei_raw;
    const long long* as64 = (const long long*)ei_raw;
    bool is64 = true;
    for (int k = 0; k < 16; ++k) {
        long long v = as64[k];
        if (!(v >= 0 && v < 2147483648LL)) { is64 = false; }
    }
    if (i < E) {
        int s, d;
        if (is64) {
            s = (int)as64[i];
            d = (int)as64[(size_t)E + i];
        } else {
            s = as32[i];
            d = as32[(size_t)E + i];
        }
        int p = atomicAdd(&cnt[d], 1);
        if (p < CAP) {
            bucket[(size_t)d * CAP + p] = s;
        } else {
            int q = atomicAdd(ovf_cnt, 1);
            ovf_src[q] = s;
            ovf_dst[q] = d;
        }
    }
}

// ---------------------------------------------------------------------------
// Split-bf16 MFMA GEMM body + fused alpha epilogue (see R10 notes).
// ---------------------------------------------------------------------------
template <int H, bool BF16OUT>
__device__ inline void gemm_body(int bid, const float* __restrict__ X,
                                 const unsigned short* __restrict__ wf_hi,
                                 const unsigned short* __restrict__ wf_lo,
                                 const float* __restrict__ asrc,
                                 const float* __restrict__ adst,
                                 void* __restrict__ Hout,
                                 float* __restrict__ alpha_s,
                                 float* __restrict__ alpha_d, int N) {
    int t = threadIdx.x;
    int wv = t >> 6;
    int l = t & 63;
    int m = l & 15;
    int quad = l >> 4;
    int row0 = bid * 64 + wv * 16;

    f32x4 acc[8];
#pragma unroll
    for (int ct = 0; ct < 8; ++ct) acc[ct] = (f32x4){0.f, 0.f, 0.f, 0.f};

    int arow = row0 + m;
    bool okA = arow < N;
    const float4* X4 = (const float4*)X;

    for (int kstep = 0; kstep < 4; ++kstep) {
        float4 a0 = make_float4(0.f, 0.f, 0.f, 0.f);
        float4 a1 = make_float4(0.f, 0.f, 0.f, 0.f);
        if (okA) {
            a0 = X4[(size_t)arow * 32 + kstep * 8 + quad * 2];
            a1 = X4[(size_t)arow * 32 + kstep * 8 + quad * 2 + 1];
        }
        float av8[8] = {a0.x, a0.y, a0.z, a0.w, a1.x, a1.y, a1.z, a1.w};
        bf16x8 ah, al;
#pragma unroll
        for (int j = 0; j < 8; ++j) {
            unsigned short h = bf16_rne(av8[j]);
            ah[j] = (short)h;
            al[j] = (short)bf16_rne(av8[j] - bf16_tof(h));
        }
#pragma unroll
        for (int ct = 0; ct < 8; ++ct) {
            size_t boff = ((size_t)(kstep * 8 + ct) * 64 + l) * 8;
            bf16x8 bh = *(const bf16x8*)(wf_hi + boff);
            bf16x8 bl = *(const bf16x8*)(wf_lo + boff);
            acc[ct] = __builtin_amdgcn_mfma_f32_16x16x32_bf16(ah, bh, acc[ct], 0, 0, 0);
            acc[ct] = __builtin_amdgcn_mfma_f32_16x16x32_bf16(al, bh, acc[ct], 0, 0, 0);
            acc[ct] = __builtin_amdgcn_mfma_f32_16x16x32_bf16(ah, bl, acc[ct], 0, 0, 0);
        }
    }

#pragma unroll
    for (int reg = 0; reg < 4; ++reg) {
        int row = row0 + quad * 4 + reg;
        if (row < N) {
            if (BF16OUT) {
                unsigned short* hb = (unsigned short*)Hout;
#pragma unroll
                for (int ct = 0; ct < 8; ++ct)
                    hb[(size_t)row * 128 + ct * 16 + m] = bf16_rne(acc[ct][reg]);
            } else {
                float* hf = (float*)Hout;
#pragma unroll
                for (int ct = 0; ct < 8; ++ct)
                    hf[(size_t)row * 128 + ct * 16 + m] = acc[ct][reg];
            }
        }
    }

    float av[8], dv[8];
#pragma unroll
    for (int ct = 0; ct < 8; ++ct) {
        av[ct] = asrc[ct * 16 + m];
        dv[ct] = adst[ct * 16 + m];
    }
#pragma unroll
    for (int reg = 0; reg < 4; ++reg) {
        int row = row0 + quad * 4 + reg;
        if (H == 4) {
            float ps[4], pd[4];
#pragma unroll
            for (int hh = 0; hh < 4; ++hh) {
                ps[hh] = acc[2 * hh][reg] * av[2 * hh] +
                         acc[2 * hh + 1][reg] * av[2 * hh + 1];
                pd[hh] = acc[2 * hh][reg] * dv[2 * hh] +
                         acc[2 * hh + 1][reg] * dv[2 * hh + 1];
            }
#pragma unroll
            for (int o = 1; o < 16; o <<= 1) {
#pragma unroll
                for (int hh = 0; hh < 4; ++hh) {
                    ps[hh] += __shfl_xor(ps[hh], o);
                    pd[hh] += __shfl_xor(pd[hh], o);
                }
            }
            if (m == 0 && row < N) {
#pragma unroll
                for (int hh = 0; hh < 4; ++hh) {
                    alpha_s[(size_t)row * 4 + hh] = ps[hh];
                    alpha_d[(size_t)row * 4 + hh] = pd[hh];
                }
            }
        } else {
            float ps = 0.f, pd = 0.f;
#pragma unroll
            for (int ct = 0; ct < 8; ++ct) {
                ps += acc[ct][reg] * av[ct];
                pd += acc[ct][reg] * dv[ct];
            }
#pragma unroll
            for (int o = 1; o < 16; o <<= 1) {
                ps += __shfl_xor(ps, o);
                pd += __shfl_xor(pd, o);
            }
            if (m == 0 && row < N) {
                alpha_s[row] = ps;
                alpha_d[row] = pd;
            }
        }
    }
}

// Fused build + layer-0 gemm. BUILD BLOCKS FIRST: build is the long pole
// (latency-bound); starting it at t=0 lets the gemm fill in behind it
// (R11 had gemm first: build start delayed + 95us total).
template <int H, bool BF16OUT>
__global__ __launch_bounds__(256) void gemm_build_kernel(
    const float* __restrict__ X, const unsigned short* __restrict__ wf_hi,
    const unsigned short* __restrict__ wf_lo, const float* __restrict__ asrc,
    const float* __restrict__ adst, void* __restrict__ Hout,
    float* __restrict__ alpha_s, float* __restrict__ alpha_d, int N, int eb,
    const void* __restrict__ ei_raw, int E, int* __restrict__ cnt,
    int* __restrict__ bucket, int* __restrict__ ovf_src,
    int* __restrict__ ovf_dst, int* __restrict__ ovf_cnt) {
    if ((int)blockIdx.x < eb) {
        int i = (int)blockIdx.x * 256 + threadIdx.x;
        build_body(i, ei_raw, E, cnt, bucket, ovf_src, ovf_dst, ovf_cnt);
    } else {
        gemm_body<H, BF16OUT>((int)blockIdx.x - eb, X, wf_hi, wf_lo, asrc,
                              adst, Hout, alpha_s, alpha_d, N);
    }
}

template <int H, bool BF16OUT>
__global__ __launch_bounds__(256) void gemm_kernel(
    const float* __restrict__ X, const unsigned short* __restrict__ wf_hi,
    const unsigned short* __restrict__ wf_lo, const float* __restrict__ asrc,
    const float* __restrict__ adst, void* __restrict__ Hout,
    float* __restrict__ alpha_s, float* __restrict__ alpha_d, int N) {
    gemm_body<H, BF16OUT>(blockIdx.x, X, wf_hi, wf_lo, asrc, adst, Hout,
                          alpha_s, alpha_d, N);
}

// ---------------------------------------------------------------------------
// Segment softmax + aggregation. Two nodes per wave (32 lanes each).
// BF16IN Phase C: a bf16 row is 256B = 16 lanes x 16B, so each half-wave
// processes TWO edges per load instruction (lane = parity g x channel c);
// partial sums folded by xor-16 at the end. fp32 path: one row per half.
// ---------------------------------------------------------------------------
template <int H, bool BF16IN>
__global__ __launch_bounds__(128) void gather_kernel(
    const void* __restrict__ hvp, const float* __restrict__ as_,
    const float* __restrict__ ad_, const int* __restrict__ cnt,
    const int* __restrict__ bucket, const int* __restrict__ ovf_src,
    const int* __restrict__ ovf_dst, const int* __restrict__ ovf_cnt,
    const float* __restrict__ bias, float* __restrict__ out, int N) {
    __shared__ int s_src[4][32];
    __shared__ float s_w[4][32 * H];
    int t = threadIdx.x;
    int wv = t >> 6;
    int lane = t & 63;
    int hw = lane >> 5;
    int l = lane & 31;
    int sub = wv * 2 + hw;
    int n = blockIdx.x * 4 + sub;
    if (n >= N) return;

    int deg = cnt[n];
    int total = deg + 1;
    int totalb = min(deg, CAP) + 1;
    int onum = (deg > CAP) ? *ovf_cnt : 0;
    const int* bk = bucket + (size_t)n * CAP;

    float adv[H];
#pragma unroll
    for (int hh = 0; hh < H; ++hh) adv[hh] = ad_[(size_t)n * H + hh];

    float sv[H];
    float m[H];
#pragma unroll
    for (int hh = 0; hh < H; ++hh) m[hh] = -3.4e38f;
    int total0 = min(total, 32);
    if (l < total0) {
        int src = (l == 0) ? n : bk[l - 1];
        s_src[sub][l] = src;
        if (H == 4) {
            float4 a4 = ((const float4*)as_)[src];
            sv[0] = a4.x + adv[0];
            sv[1] = a4.y + adv[1];
            sv[2] = a4.z + adv[2];
            sv[3] = a4.w + adv[3];
        } else {
            sv[0] = as_[src] + adv[0];
        }
#pragma unroll
        for (int hh = 0; hh < H; ++hh) {
            float s = sv[hh];
            s = (s > 0.f) ? s : NEG_SLOPE * s;
            sv[hh] = s;
            m[hh] = s;
        }
    }
    for (int idx = l + 32; idx < totalb; idx += 32) {
        int src = bk[idx - 1];
#pragma unroll
        for (int hh = 0; hh < H; ++hh) {
            float s = as_[(size_t)src * H + hh] + adv[hh];
            s = (s > 0.f) ? s : NEG_SLOPE * s;
            m[hh] = fmaxf(m[hh], s);
        }
    }
    for (int e = 0; e < onum; ++e) {
        if (ovf_dst[e] == n && l == 0) {
            int src = ovf_src[e];
#pragma unroll
            for (int hh = 0; hh < H; ++hh) {
                float s = as_[(size_t)src * H + hh] + adv[hh];
                s = (s > 0.f) ? s : NEG_SLOPE * s;
                m[hh] = fmaxf(m[hh], s);
            }
        }
    }
#pragma unroll
    for (int o = 16; o > 0; o >>= 1)
#pragma unroll
        for (int hh = 0; hh < H; ++hh) m[hh] = fmaxf(m[hh], __shfl_xor(m[hh], o));

    float p[H];
    float dsum[H];
#pragma unroll
    for (int hh = 0; hh < H; ++hh) dsum[hh] = 0.f;
    if (l < total0) {
#pragma unroll
        for (int hh = 0; hh < H; ++hh) {
            p[hh] = __expf(sv[hh] - m[hh]);
            dsum[hh] = p[hh];
        }
    }
    for (int idx = l + 32; idx < totalb; idx += 32) {
        int src = bk[idx - 1];
#pragma unroll
        for (int hh = 0; hh < H; ++hh) {
            float s = as_[(size_t)src * H + hh] + adv[hh];
            s = (s > 0.f) ? s : NEG_SLOPE * s;
            dsum[hh] += __expf(s - m[hh]);
        }
    }
    for (int e = 0; e < onum; ++e) {
        if (ovf_dst[e] == n && l == 0) {
            int src = ovf_src[e];
#pragma unroll
            for (int hh = 0; hh < H; ++hh) {
                float s = as_[(size_t)src * H + hh] + adv[hh];
                s = (s > 0.f) ? s : NEG_SLOPE * s;
                dsum[hh] += __expf(s - m[hh]);
            }
        }
    }
#pragma unroll
    for (int o = 16; o > 0; o >>= 1)
#pragma unroll
        for (int hh = 0; hh < H; ++hh) dsum[hh] += __shfl_xor(dsum[hh], o);
    float inv[H];
#pragma unroll
    for (int hh = 0; hh < H; ++hh) inv[hh] = 1.f / dsum[hh];

    if (l < total0) {
#pragma unroll
        for (int hh = 0; hh < H; ++hh) s_w[sub][l * H + hh] = p[hh] * inv[hh];
    }

    if (BF16IN) {
        // Phase C, 2 edges/half-wave: g = edge parity, c = channel group (8ch)
        int g = l >> 4;
        int c = l & 15;
        const int head_c = (H == 1) ? 0 : (c >> 2);  // (c*8)/32 for H=4
        float a8[8];
#pragma unroll
        for (int k = 0; k < 8; ++k) a8[k] = 0.f;
        const uint4* __restrict__ hb4 = (const uint4*)hvp;
        for (int base = 0; base < totalb; base += 32) {
            int cnt2 = min(32, totalb - base);
            if (base > 0 && l < cnt2) {
                int src = bk[base + l - 1];
                s_src[sub][l] = src;
#pragma unroll
                for (int hh = 0; hh < H; ++hh) {
                    float s = as_[(size_t)src * H + hh] + adv[hh];
                    s = (s > 0.f) ? s : NEG_SLOPE * s;
                    s_w[sub][l * H + hh] = __expf(s - m[hh]) * inv[hh];
                }
            }
            __builtin_amdgcn_wave_barrier();
            int j = 0;
            for (; j + 8 <= cnt2; j += 8) {
                int ts[4];
                float ws[4];
                uint4 rv[4];
#pragma unroll
                for (int u = 0; u < 4; ++u) {
                    int e = j + 2 * u + g;
                    ts[u] = s_src[sub][e];
                    ws[u] = s_w[sub][e * H + head_c];
                }
#pragma unroll
                for (int u = 0; u < 4; ++u) rv[u] = hb4[(size_t)ts[u] * 16 + c];
#pragma unroll
                for (int u = 0; u < 4; ++u) {
                    a8[0] += ws[u] * __uint_as_float(rv[u].x << 16);
                    a8[1] += ws[u] * __uint_as_float(rv[u].x & 0xFFFF0000u);
                    a8[2] += ws[u] * __uint_as_float(rv[u].y << 16);
                    a8[3] += ws[u] * __uint_as_float(rv[u].y & 0xFFFF0000u);
                    a8[4] += ws[u] * __uint_as_float(rv[u].z << 16);
                    a8[5] += ws[u] * __uint_as_float(rv[u].z & 0xFFFF0000u);
                    a8[6] += ws[u] * __uint_as_float(rv[u].w << 16);
                    a8[7] += ws[u] * __uint_as_float(rv[u].w & 0xFFFF0000u);
                }
            }
            for (; j < cnt2; j += 2) {
                int e = j + g;
                if (e < cnt2) {
                    int sj = s_src[sub][e];
                    float wj = s_w[sub][e * H + head_c];
                    uint4 rv = hb4[(size_t)sj * 16 + c];
                    a8[0] += wj * __uint_as_float(rv.x << 16);
                    a8[1] += wj * __uint_as_float(rv.x & 0xFFFF0000u);
                    a8[2] += wj * __uint_as_float(rv.y << 16);
                    a8[3] += wj * __uint_as_float(rv.y & 0xFFFF0000u);
                    a8[4] += wj * __uint_as_float(rv.z << 16);
                    a8[5] += wj * __uint_as_float(rv.z & 0xFFFF0000u);
                    a8[6] += wj * __uint_as_float(rv.w << 16);
                    a8[7] += wj * __uint_as_float(rv.w & 0xFFFF0000u);
                }
            }
            __builtin_amdgcn_wave_barrier();
        }
        for (int e = 0; e < onum; ++e) {  // overflow: g==0 lanes only
            if (ovf_dst[e] == n && g == 0) {
                int src = ovf_src[e];
                float s = as_[(size_t)src * H + head_c] + adv[head_c];
                s = (s > 0.f) ? s : NEG_SLOPE * s;
                float wj = __expf(s - m[head_c]) * inv[head_c];
                uint4 rv = hb4[(size_t)src * 16 + c];
                a8[0] += wj * __uint_as_float(rv.x << 16);
                a8[1] += wj * __uint_as_float(rv.x & 0xFFFF0000u);
                a8[2] += wj * __uint_as_float(rv.y << 16);
                a8[3] += wj * __uint_as_float(rv.y & 0xFFFF0000u);
                a8[4] += wj * __uint_as_float(rv.z << 16);
                a8[5] += wj * __uint_as_float(rv.z & 0xFFFF0000u);
                a8[6] += wj * __uint_as_float(rv.w << 16);
                a8[7] += wj * __uint_as_float(rv.w & 0xFFFF0000u);
            }
        }
        // fold edge-parity partials
#pragma unroll
        for (int k = 0; k < 8; ++k) a8[k] += __shfl_xor(a8[k], 16);
        if (g == 0) {
            float4 o0, o1;
            o0.x = fmaxf(a8[0] + bias[c * 8 + 0], 0.f);
            o0.y = fmaxf(a8[1] + bias[c * 8 + 1], 0.f);
            o0.z = fmaxf(a8[2] + bias[c * 8 + 2], 0.f);
            o0.w = fmaxf(a8[3] + bias[c * 8 + 3], 0.f);
            o1.x = fmaxf(a8[4] + bias[c * 8 + 4], 0.f);
            o1.y = fmaxf(a8[5] + bias[c * 8 + 5], 0.f);
            o1.z = fmaxf(a8[6] + bias[c * 8 + 6], 0.f);
            o1.w = fmaxf(a8[7] + bias[c * 8 + 7], 0.f);
            ((float4*)out)[(size_t)n * 32 + c * 2] = o0;
            ((float4*)out)[(size_t)n * 32 + c * 2 + 1] = o1;
        }
    } else {
        const int head_t = (H == 1) ? 0 : (l >> 3);
        float4 acc = make_float4(0.f, 0.f, 0.f, 0.f);
        const float4* __restrict__ h4 = (const float4*)hvp;
        for (int base = 0; base < totalb; base += 32) {
            int cnt2 = min(32, totalb - base);
            if (base > 0 && l < cnt2) {
                int src = bk[base + l - 1];
                s_src[sub][l] = src;
#pragma unroll
                for (int hh = 0; hh < H; ++hh) {
                    float s = as_[(size_t)src * H + hh] + adv[hh];
                    s = (s > 0.f) ? s : NEG_SLOPE * s;
                    s_w[sub][l * H + hh] = __expf(s - m[hh]) * inv[hh];
                }
            }
            __builtin_amdgcn_wave_barrier();
            int j = 0;
            for (; j + 8 <= cnt2; j += 8) {
                int ts[8];
                float ws[8];
                float4 vs[8];
#pragma unroll
                for (int u = 0; u < 8; ++u) {
                    ts[u] = s_src[sub][j + u];
                    ws[u] = s_w[sub][(j + u) * H + head_t];
                }
#pragma unroll
                for (int u = 0; u < 8; ++u) vs[u] = h4[(size_t)ts[u] * 32 + l];
#pragma unroll
                for (int u = 0; u < 8; ++u) {
                    acc.x += ws[u] * vs[u].x;
                    acc.y += ws[u] * vs[u].y;
                    acc.z += ws[u] * vs[u].z;
                    acc.w += ws[u] * vs[u].w;
                }
            }
            for (; j < cnt2; ++j) {
                int sj = s_src[sub][j];
                float wj = s_w[sub][j * H + head_t];
                float4 hv = h4[(size_t)sj * 32 + l];
                acc.x += wj * hv.x; acc.y += wj * hv.y;
                acc.z += wj * hv.z; acc.w += wj * hv.w;
            }
            __builtin_amdgcn_wave_barrier();
        }
        for (int e = 0; e < onum; ++e) {
            if (ovf_dst[e] == n) {
                int src = ovf_src[e];
                int hh = head_t;
                float s = as_[(size_t)src * H + hh] + adv[hh];
                s = (s > 0.f) ? s : NEG_SLOPE * s;
                float wj = __expf(s - m[hh]) * inv[hh];
                float4 hv = h4[(size_t)src * 32 + l];
                acc.x += wj * hv.x; acc.y += wj * hv.y;
                acc.z += wj * hv.z; acc.w += wj * hv.w;
            }
        }
        float4 bv = ((const float4*)bias)[l];
        float4 o4;
        o4.x = fmaxf(acc.x + bv.x, 0.f);
        o4.y = fmaxf(acc.y + bv.y, 0.f);
        o4.z = fmaxf(acc.z + bv.z, 0.f);
        o4.w = fmaxf(acc.w + bv.w, 0.f);
        ((float4*)out)[(size_t)n * 32 + l] = o4;
    }
}

// ---------------------------------------------------------------------------
extern "C" void kernel_launch(void* const* d_in, const int* in_sizes, int n_in,
                              void* d_out, int out_size, void* d_ws,
                              size_t ws_size, hipStream_t stream) {
    const float* x   = (const float*)d_in[0];
    const void*  ei  = d_in[1];
    const float* W0  = (const float*)d_in[2];
    const float* as0 = (const float*)d_in[3];
    const float* ad0 = (const float*)d_in[4];
    const float* b0  = (const float*)d_in[5];
    const float* W1  = (const float*)d_in[6];
    const float* as1 = (const float*)d_in[7];
    const float* ad1 = (const float*)d_in[8];
    const float* b1  = (const float*)d_in[9];
    const float* W2  = (const float*)d_in[10];
    const float* as2 = (const float*)d_in[11];
    const float* ad2 = (const float*)d_in[12];
    const float* b2  = (const float*)d_in[13];

    int N = in_sizes[0] / 128;
    int E = in_sizes[1] / 2;
    float* out = (float*)d_out;

    float* h       = (float*)d_ws;                       // N*128 f32
    float* alpha_s = h + (size_t)N * 128;                // N*4 (max H)
    float* alpha_d = alpha_s + (size_t)N * 4;            // N*4
    int*   cnt     = (int*)(alpha_d + (size_t)N * 4);    // N
    int*   ovf_c   = cnt + N;                            // 1
    int*   bucket  = ovf_c + 1;                          // N*CAP
    int*   ovf_src = bucket + (size_t)N * CAP;           // E
    int*   ovf_dst = ovf_src + E;                        // E
    unsigned short* wf = (unsigned short*)(ovf_dst + E); // 3*32768 ushort

    int eb = (E + 255) / 256;
    int nb = (N + 1 + 255) / 256;
    int gb = (N + 63) / 64;
    int wb = (N + 3) / 4;

    prep_kernel<<<24 + nb, 256, 0, stream>>>(W0, W1, W2, wf, cnt, N + 1);

    // layer 0 gemm fused with adjacency build (build blocks first)
    gemm_build_kernel<4, true><<<eb + gb, 256, 0, stream>>>(
        x, wf, wf + 16384, as0, ad0, h, alpha_s, alpha_d, N, eb,
        ei, E, cnt, bucket, ovf_src, ovf_dst, ovf_c);
    gather_kernel<4, true><<<wb, 128, 0, stream>>>(h, alpha_s, alpha_d, cnt,
                                                   bucket, ovf_src, ovf_dst,
                                                   ovf_c, b0, out, N);

    // layer 1
    gemm_kernel<4, true><<<gb, 256, 0, stream>>>(out, wf + 32768, wf + 49152,
                                                 as1, ad1, h, alpha_s, alpha_d, N);
    gather_kernel<4, true><<<wb, 128, 0, stream>>>(h, alpha_s, alpha_d, cnt,
                                                   bucket, ovf_src, ovf_dst,
                                                   ovf_c, b1, out, N);

    // layer 2 (H=1, fp32 h — final aggregation kept full precision)
    gemm_kernel<1, false><<<gb, 256, 0, stream>>>(out, wf + 65536, wf + 81920,
                                                  as2, ad2, h, alpha_s, alpha_d, N);
    gather_kernel<1, false><<<wb, 128, 0, stream>>>(h, alpha_s, alpha_d, cnt,
                                                    bucket, ovf_src, ovf_dst,
                                                    ovf_c, b2, out, N);
}

// Round 13
// 353.470 us; speedup vs baseline: 1.0401x; 1.0401x over previous
//
#include <hip/hip_runtime.h>

#define NEG_SLOPE 0.2f
#define CAP 64  // bucket capacity per node; overflow handled exactly

using f32x4 = __attribute__((ext_vector_type(4))) float;
using bf16x8 = __attribute__((ext_vector_type(8))) short;

__device__ inline unsigned short bf16_rne(float f) {
    unsigned int u = __float_as_uint(f);
    return (unsigned short)((u + 0x7FFF + ((u >> 16) & 1)) >> 16);
}
__device__ inline float bf16_tof(unsigned short h) {
    return __uint_as_float(((unsigned int)h) << 16);
}

// ---------------------------------------------------------------------------
// prep: wprep (first 24 blocks) + zero cnt/ovf (rest).
// ---------------------------------------------------------------------------
__global__ void prep_kernel(const float* __restrict__ W0,
                            const float* __restrict__ W1,
                            const float* __restrict__ W2,
                            unsigned short* __restrict__ wf,
                            int* __restrict__ cnt, int nz) {
    if (blockIdx.x < 24) {
        int tid = blockIdx.x * 256 + threadIdx.x;
        if (tid >= 3 * 2048) return;
        int layer = tid >> 11;
        int rem = tid & 2047;
        int kstep = rem >> 9;
        int ct = (rem >> 6) & 7;
        int lane = rem & 63;
        const float* W = (layer == 0) ? W0 : (layer == 1) ? W1 : W2;
        unsigned short* hi = wf + (size_t)layer * 32768 +
                             ((size_t)(kstep * 8 + ct) * 64 + lane) * 8;
        unsigned short* lo = hi + 16384;
#pragma unroll
        for (int j = 0; j < 8; ++j) {
            int k = kstep * 32 + (lane >> 4) * 8 + j;
            int n = ct * 16 + (lane & 15);
            float f = W[k * 128 + n];
            unsigned short h = bf16_rne(f);
            hi[j] = h;
            lo[j] = bf16_rne(f - bf16_tof(h));
        }
    } else {
        int i = (blockIdx.x - 24) * 256 + threadIdx.x;
        if (i < nz) cnt[i] = 0;
    }
}

// ---------------------------------------------------------------------------
// Standalone adjacency build: 1 edge/thread, 8 VGPR, full occupancy.
// (Fusion with gemm0 regressed twice: gemm's VGPR-68 allocation cut build
// occupancy 61%->26% — R11/R12. Atomic-throughput floor ~66us.)
// ---------------------------------------------------------------------------
__global__ void build_kernel(const void* __restrict__ ei_raw, int E,
                             int* __restrict__ cnt, int* __restrict__ bucket,
                             int* __restrict__ ovf_src,
                             int* __restrict__ ovf_dst,
                             int* __restrict__ ovf_cnt) {
    const int* as32 = (const int*)ei_raw;
    const long long* as64 = (const long long*)ei_raw;
    bool is64 = true;
    for (int k = 0; k < 16; ++k) {
        long long v = as64[k];
        if (!(v >= 0 && v < 2147483648LL)) { is64 = false; }
    }
    int i = blockIdx.x * blockDim.x + threadIdx.x;
    if (i < E) {
        int s, d;
        if (is64) {
            s = (int)as64[i];
            d = (int)as64[(size_t)E + i];
        } else {
            s = as32[i];
            d = as32[(size_t)E + i];
        }
        int p = atomicAdd(&cnt[d], 1);
        if (p < CAP) {
            bucket[(size_t)d * CAP + p] = s;
        } else {
            int q = atomicAdd(ovf_cnt, 1);
            ovf_src[q] = s;
            ovf_dst[q] = d;
        }
    }
}

// ---------------------------------------------------------------------------
// Split-bf16 MFMA GEMM + fused alpha epilogue (R10 structure).
// ---------------------------------------------------------------------------
template <int H, bool BF16OUT>
__global__ __launch_bounds__(256) void gemm_kernel(
    const float* __restrict__ X, const unsigned short* __restrict__ wf_hi,
    const unsigned short* __restrict__ wf_lo, const float* __restrict__ asrc,
    const float* __restrict__ adst, void* __restrict__ Hout,
    float* __restrict__ alpha_s, float* __restrict__ alpha_d, int N) {
    int t = threadIdx.x;
    int wv = t >> 6;
    int l = t & 63;
    int m = l & 15;
    int quad = l >> 4;
    int row0 = blockIdx.x * 64 + wv * 16;

    f32x4 acc[8];
#pragma unroll
    for (int ct = 0; ct < 8; ++ct) acc[ct] = (f32x4){0.f, 0.f, 0.f, 0.f};

    int arow = row0 + m;
    bool okA = arow < N;
    const float4* X4 = (const float4*)X;

    for (int kstep = 0; kstep < 4; ++kstep) {
        float4 a0 = make_float4(0.f, 0.f, 0.f, 0.f);
        float4 a1 = make_float4(0.f, 0.f, 0.f, 0.f);
        if (okA) {
            a0 = X4[(size_t)arow * 32 + kstep * 8 + quad * 2];
            a1 = X4[(size_t)arow * 32 + kstep * 8 + quad * 2 + 1];
        }
        float av8[8] = {a0.x, a0.y, a0.z, a0.w, a1.x, a1.y, a1.z, a1.w};
        bf16x8 ah, al;
#pragma unroll
        for (int j = 0; j < 8; ++j) {
            unsigned short h = bf16_rne(av8[j]);
            ah[j] = (short)h;
            al[j] = (short)bf16_rne(av8[j] - bf16_tof(h));
        }
#pragma unroll
        for (int ct = 0; ct < 8; ++ct) {
            size_t boff = ((size_t)(kstep * 8 + ct) * 64 + l) * 8;
            bf16x8 bh = *(const bf16x8*)(wf_hi + boff);
            bf16x8 bl = *(const bf16x8*)(wf_lo + boff);
            acc[ct] = __builtin_amdgcn_mfma_f32_16x16x32_bf16(ah, bh, acc[ct], 0, 0, 0);
            acc[ct] = __builtin_amdgcn_mfma_f32_16x16x32_bf16(al, bh, acc[ct], 0, 0, 0);
            acc[ct] = __builtin_amdgcn_mfma_f32_16x16x32_bf16(ah, bl, acc[ct], 0, 0, 0);
        }
    }

#pragma unroll
    for (int reg = 0; reg < 4; ++reg) {
        int row = row0 + quad * 4 + reg;
        if (row < N) {
            if (BF16OUT) {
                unsigned short* hb = (unsigned short*)Hout;
#pragma unroll
                for (int ct = 0; ct < 8; ++ct)
                    hb[(size_t)row * 128 + ct * 16 + m] = bf16_rne(acc[ct][reg]);
            } else {
                float* hf = (float*)Hout;
#pragma unroll
                for (int ct = 0; ct < 8; ++ct)
                    hf[(size_t)row * 128 + ct * 16 + m] = acc[ct][reg];
            }
        }
    }

    float av[8], dv[8];
#pragma unroll
    for (int ct = 0; ct < 8; ++ct) {
        av[ct] = asrc[ct * 16 + m];
        dv[ct] = adst[ct * 16 + m];
    }
#pragma unroll
    for (int reg = 0; reg < 4; ++reg) {
        int row = row0 + quad * 4 + reg;
        if (H == 4) {
            float ps[4], pd[4];
#pragma unroll
            for (int hh = 0; hh < 4; ++hh) {
                ps[hh] = acc[2 * hh][reg] * av[2 * hh] +
                         acc[2 * hh + 1][reg] * av[2 * hh + 1];
                pd[hh] = acc[2 * hh][reg] * dv[2 * hh] +
                         acc[2 * hh + 1][reg] * dv[2 * hh + 1];
            }
#pragma unroll
            for (int o = 1; o < 16; o <<= 1) {
#pragma unroll
                for (int hh = 0; hh < 4; ++hh) {
                    ps[hh] += __shfl_xor(ps[hh], o);
                    pd[hh] += __shfl_xor(pd[hh], o);
                }
            }
            if (m == 0 && row < N) {
#pragma unroll
                for (int hh = 0; hh < 4; ++hh) {
                    alpha_s[(size_t)row * 4 + hh] = ps[hh];
                    alpha_d[(size_t)row * 4 + hh] = pd[hh];
                }
            }
        } else {
            float ps = 0.f, pd = 0.f;
#pragma unroll
            for (int ct = 0; ct < 8; ++ct) {
                ps += acc[ct][reg] * av[ct];
                pd += acc[ct][reg] * dv[ct];
            }
#pragma unroll
            for (int o = 1; o < 16; o <<= 1) {
                ps += __shfl_xor(ps, o);
                pd += __shfl_xor(pd, o);
            }
            if (m == 0 && row < N) {
                alpha_s[row] = ps;
                alpha_d[row] = pd;
            }
        }
    }
}

// ---------------------------------------------------------------------------
// Segment softmax + aggregation. Two nodes per wave (32 lanes each).
// BF16IN Phase C: bf16 row = 256B = 16 lanes x 16B -> 2 edges per load
// instruction per half-wave (lane = parity g x channel group c); partials
// folded by xor-16. fp32 path: one row per half-wave, x8 unroll.
// ---------------------------------------------------------------------------
template <int H, bool BF16IN>
__global__ __launch_bounds__(128) void gather_kernel(
    const void* __restrict__ hvp, const float* __restrict__ as_,
    const float* __restrict__ ad_, const int* __restrict__ cnt,
    const int* __restrict__ bucket, const int* __restrict__ ovf_src,
    const int* __restrict__ ovf_dst, const int* __restrict__ ovf_cnt,
    const float* __restrict__ bias, float* __restrict__ out, int N) {
    __shared__ int s_src[4][32];
    __shared__ float s_w[4][32 * H];
    int t = threadIdx.x;
    int wv = t >> 6;
    int lane = t & 63;
    int hw = lane >> 5;
    int l = lane & 31;
    int sub = wv * 2 + hw;
    int n = blockIdx.x * 4 + sub;
    if (n >= N) return;

    int deg = cnt[n];
    int total = deg + 1;
    int totalb = min(deg, CAP) + 1;
    int onum = (deg > CAP) ? *ovf_cnt : 0;
    const int* bk = bucket + (size_t)n * CAP;

    float adv[H];
#pragma unroll
    for (int hh = 0; hh < H; ++hh) adv[hh] = ad_[(size_t)n * H + hh];

    float sv[H];
    float m[H];
#pragma unroll
    for (int hh = 0; hh < H; ++hh) m[hh] = -3.4e38f;
    int total0 = min(total, 32);
    if (l < total0) {
        int src = (l == 0) ? n : bk[l - 1];
        s_src[sub][l] = src;
        if (H == 4) {
            float4 a4 = ((const float4*)as_)[src];
            sv[0] = a4.x + adv[0];
            sv[1] = a4.y + adv[1];
            sv[2] = a4.z + adv[2];
            sv[3] = a4.w + adv[3];
        } else {
            sv[0] = as_[src] + adv[0];
        }
#pragma unroll
        for (int hh = 0; hh < H; ++hh) {
            float s = sv[hh];
            s = (s > 0.f) ? s : NEG_SLOPE * s;
            sv[hh] = s;
            m[hh] = s;
        }
    }
    for (int idx = l + 32; idx < totalb; idx += 32) {
        int src = bk[idx - 1];
#pragma unroll
        for (int hh = 0; hh < H; ++hh) {
            float s = as_[(size_t)src * H + hh] + adv[hh];
            s = (s > 0.f) ? s : NEG_SLOPE * s;
            m[hh] = fmaxf(m[hh], s);
        }
    }
    for (int e = 0; e < onum; ++e) {
        if (ovf_dst[e] == n && l == 0) {
            int src = ovf_src[e];
#pragma unroll
            for (int hh = 0; hh < H; ++hh) {
                float s = as_[(size_t)src * H + hh] + adv[hh];
                s = (s > 0.f) ? s : NEG_SLOPE * s;
                m[hh] = fmaxf(m[hh], s);
            }
        }
    }
#pragma unroll
    for (int o = 16; o > 0; o >>= 1)
#pragma unroll
        for (int hh = 0; hh < H; ++hh) m[hh] = fmaxf(m[hh], __shfl_xor(m[hh], o));

    float p[H];
    float dsum[H];
#pragma unroll
    for (int hh = 0; hh < H; ++hh) dsum[hh] = 0.f;
    if (l < total0) {
#pragma unroll
        for (int hh = 0; hh < H; ++hh) {
            p[hh] = __expf(sv[hh] - m[hh]);
            dsum[hh] = p[hh];
        }
    }
    for (int idx = l + 32; idx < totalb; idx += 32) {
        int src = bk[idx - 1];
#pragma unroll
        for (int hh = 0; hh < H; ++hh) {
            float s = as_[(size_t)src * H + hh] + adv[hh];
            s = (s > 0.f) ? s : NEG_SLOPE * s;
            dsum[hh] += __expf(s - m[hh]);
        }
    }
    for (int e = 0; e < onum; ++e) {
        if (ovf_dst[e] == n && l == 0) {
            int src = ovf_src[e];
#pragma unroll
            for (int hh = 0; hh < H; ++hh) {
                float s = as_[(size_t)src * H + hh] + adv[hh];
                s = (s > 0.f) ? s : NEG_SLOPE * s;
                dsum[hh] += __expf(s - m[hh]);
            }
        }
    }
#pragma unroll
    for (int o = 16; o > 0; o >>= 1)
#pragma unroll
        for (int hh = 0; hh < H; ++hh) dsum[hh] += __shfl_xor(dsum[hh], o);
    float inv[H];
#pragma unroll
    for (int hh = 0; hh < H; ++hh) inv[hh] = 1.f / dsum[hh];

    if (l < total0) {
#pragma unroll
        for (int hh = 0; hh < H; ++hh) s_w[sub][l * H + hh] = p[hh] * inv[hh];
    }

    if (BF16IN) {
        int g = l >> 4;
        int c = l & 15;
        const int head_c = (H == 1) ? 0 : (c >> 2);
        float a8[8];
#pragma unroll
        for (int k = 0; k < 8; ++k) a8[k] = 0.f;
        const uint4* __restrict__ hb4 = (const uint4*)hvp;
        for (int base = 0; base < totalb; base += 32) {
            int cnt2 = min(32, totalb - base);
            if (base > 0 && l < cnt2) {
                int src = bk[base + l - 1];
                s_src[sub][l] = src;
#pragma unroll
                for (int hh = 0; hh < H; ++hh) {
                    float s = as_[(size_t)src * H + hh] + adv[hh];
                    s = (s > 0.f) ? s : NEG_SLOPE * s;
                    s_w[sub][l * H + hh] = __expf(s - m[hh]) * inv[hh];
                }
            }
            __builtin_amdgcn_wave_barrier();
            int j = 0;
            for (; j + 8 <= cnt2; j += 8) {
                int ts[4];
                float ws[4];
                uint4 rv[4];
#pragma unroll
                for (int u = 0; u < 4; ++u) {
                    int e = j + 2 * u + g;
                    ts[u] = s_src[sub][e];
                    ws[u] = s_w[sub][e * H + head_c];
                }
#pragma unroll
                for (int u = 0; u < 4; ++u) rv[u] = hb4[(size_t)ts[u] * 16 + c];
#pragma unroll
                for (int u = 0; u < 4; ++u) {
                    a8[0] += ws[u] * __uint_as_float(rv[u].x << 16);
                    a8[1] += ws[u] * __uint_as_float(rv[u].x & 0xFFFF0000u);
                    a8[2] += ws[u] * __uint_as_float(rv[u].y << 16);
                    a8[3] += ws[u] * __uint_as_float(rv[u].y & 0xFFFF0000u);
                    a8[4] += ws[u] * __uint_as_float(rv[u].z << 16);
                    a8[5] += ws[u] * __uint_as_float(rv[u].z & 0xFFFF0000u);
                    a8[6] += ws[u] * __uint_as_float(rv[u].w << 16);
                    a8[7] += ws[u] * __uint_as_float(rv[u].w & 0xFFFF0000u);
                }
            }
            for (; j < cnt2; j += 2) {
                int e = j + g;
                if (e < cnt2) {
                    int sj = s_src[sub][e];
                    float wj = s_w[sub][e * H + head_c];
                    uint4 rv = hb4[(size_t)sj * 16 + c];
                    a8[0] += wj * __uint_as_float(rv.x << 16);
                    a8[1] += wj * __uint_as_float(rv.x & 0xFFFF0000u);
                    a8[2] += wj * __uint_as_float(rv.y << 16);
                    a8[3] += wj * __uint_as_float(rv.y & 0xFFFF0000u);
                    a8[4] += wj * __uint_as_float(rv.z << 16);
                    a8[5] += wj * __uint_as_float(rv.z & 0xFFFF0000u);
                    a8[6] += wj * __uint_as_float(rv.w << 16);
                    a8[7] += wj * __uint_as_float(rv.w & 0xFFFF0000u);
                }
            }
            __builtin_amdgcn_wave_barrier();
        }
        for (int e = 0; e < onum; ++e) {
            if (ovf_dst[e] == n && g == 0) {
                int src = ovf_src[e];
                float s = as_[(size_t)src * H + head_c] + adv[head_c];
                s = (s > 0.f) ? s : NEG_SLOPE * s;
                float wj = __expf(s - m[head_c]) * inv[head_c];
                uint4 rv = hb4[(size_t)src * 16 + c];
                a8[0] += wj * __uint_as_float(rv.x << 16);
                a8[1] += wj * __uint_as_float(rv.x & 0xFFFF0000u);
                a8[2] += wj * __uint_as_float(rv.y << 16);
                a8[3] += wj * __uint_as_float(rv.y & 0xFFFF0000u);
                a8[4] += wj * __uint_as_float(rv.z << 16);
                a8[5] += wj * __uint_as_float(rv.z & 0xFFFF0000u);
                a8[6] += wj * __uint_as_float(rv.w << 16);
                a8[7] += wj * __uint_as_float(rv.w & 0xFFFF0000u);
            }
        }
#pragma unroll
        for (int k = 0; k < 8; ++k) a8[k] += __shfl_xor(a8[k], 16);
        if (g == 0) {
            float4 o0, o1;
            o0.x = fmaxf(a8[0] + bias[c * 8 + 0], 0.f);
            o0.y = fmaxf(a8[1] + bias[c * 8 + 1], 0.f);
            o0.z = fmaxf(a8[2] + bias[c * 8 + 2], 0.f);
            o0.w = fmaxf(a8[3] + bias[c * 8 + 3], 0.f);
            o1.x = fmaxf(a8[4] + bias[c * 8 + 4], 0.f);
            o1.y = fmaxf(a8[5] + bias[c * 8 + 5], 0.f);
            o1.z = fmaxf(a8[6] + bias[c * 8 + 6], 0.f);
            o1.w = fmaxf(a8[7] + bias[c * 8 + 7], 0.f);
            ((float4*)out)[(size_t)n * 32 + c * 2] = o0;
            ((float4*)out)[(size_t)n * 32 + c * 2 + 1] = o1;
        }
    } else {
        const int head_t = (H == 1) ? 0 : (l >> 3);
        float4 acc = make_float4(0.f, 0.f, 0.f, 0.f);
        const float4* __restrict__ h4 = (const float4*)hvp;
        for (int base = 0; base < totalb; base += 32) {
            int cnt2 = min(32, totalb - base);
            if (base > 0 && l < cnt2) {
                int src = bk[base + l - 1];
                s_src[sub][l] = src;
#pragma unroll
                for (int hh = 0; hh < H; ++hh) {
                    float s = as_[(size_t)src * H + hh] + adv[hh];
                    s = (s > 0.f) ? s : NEG_SLOPE * s;
                    s_w[sub][l * H + hh] = __expf(s - m[hh]) * inv[hh];
                }
            }
            __builtin_amdgcn_wave_barrier();
            int j = 0;
            for (; j + 8 <= cnt2; j += 8) {
                int ts[8];
                float ws[8];
                float4 vs[8];
#pragma unroll
                for (int u = 0; u < 8; ++u) {
                    ts[u] = s_src[sub][j + u];
                    ws[u] = s_w[sub][(j + u) * H + head_t];
                }
#pragma unroll
                for (int u = 0; u < 8; ++u) vs[u] = h4[(size_t)ts[u] * 32 + l];
#pragma unroll
                for (int u = 0; u < 8; ++u) {
                    acc.x += ws[u] * vs[u].x;
                    acc.y += ws[u] * vs[u].y;
                    acc.z += ws[u] * vs[u].z;
                    acc.w += ws[u] * vs[u].w;
                }
            }
            for (; j < cnt2; ++j) {
                int sj = s_src[sub][j];
                float wj = s_w[sub][j * H + head_t];
                float4 hv = h4[(size_t)sj * 32 + l];
                acc.x += wj * hv.x; acc.y += wj * hv.y;
                acc.z += wj * hv.z; acc.w += wj * hv.w;
            }
            __builtin_amdgcn_wave_barrier();
        }
        for (int e = 0; e < onum; ++e) {
            if (ovf_dst[e] == n) {
                int src = ovf_src[e];
                int hh = head_t;
                float s = as_[(size_t)src * H + hh] + adv[hh];
                s = (s > 0.f) ? s : NEG_SLOPE * s;
                float wj = __expf(s - m[hh]) * inv[hh];
                float4 hv = h4[(size_t)src * 32 + l];
                acc.x += wj * hv.x; acc.y += wj * hv.y;
                acc.z += wj * hv.z; acc.w += wj * hv.w;
            }
        }
        float4 bv = ((const float4*)bias)[l];
        float4 o4;
        o4.x = fmaxf(acc.x + bv.x, 0.f);
        o4.y = fmaxf(acc.y + bv.y, 0.f);
        o4.z = fmaxf(acc.z + bv.z, 0.f);
        o4.w = fmaxf(acc.w + bv.w, 0.f);
        ((float4*)out)[(size_t)n * 32 + l] = o4;
    }
}

// ---------------------------------------------------------------------------
extern "C" void kernel_launch(void* const* d_in, const int* in_sizes, int n_in,
                              void* d_out, int out_size, void* d_ws,
                              size_t ws_size, hipStream_t stream) {
    const float* x   = (const float*)d_in[0];
    const void*  ei  = d_in[1];
    const float* W0  = (const float*)d_in[2];
    const float* as0 = (const float*)d_in[3];
    const float* ad0 = (const float*)d_in[4];
    const float* b0  = (const float*)d_in[5];
    const float* W1  = (const float*)d_in[6];
    const float* as1 = (const float*)d_in[7];
    const float* ad1 = (const float*)d_in[8];
    const float* b1  = (const float*)d_in[9];
    const float* W2  = (const float*)d_in[10];
    const float* as2 = (const float*)d_in[11];
    const float* ad2 = (const float*)d_in[12];
    const float* b2  = (const float*)d_in[13];

    int N = in_sizes[0] / 128;
    int E = in_sizes[1] / 2;
    float* out = (float*)d_out;

    float* h       = (float*)d_ws;                       // N*128 f32
    float* alpha_s = h + (size_t)N * 128;                // N*4 (max H)
    float* alpha_d = alpha_s + (size_t)N * 4;            // N*4
    int*   cnt     = (int*)(alpha_d + (size_t)N * 4);    // N
    int*   ovf_c   = cnt + N;                            // 1
    int*   bucket  = ovf_c + 1;                          // N*CAP
    int*   ovf_src = bucket + (size_t)N * CAP;           // E
    int*   ovf_dst = ovf_src + E;                        // E
    unsigned short* wf = (unsigned short*)(ovf_dst + E); // 3*32768 ushort

    int eb = (E + 255) / 256;
    int nb = (N + 1 + 255) / 256;
    int gb = (N + 63) / 64;
    int wb = (N + 3) / 4;

    prep_kernel<<<24 + nb, 256, 0, stream>>>(W0, W1, W2, wf, cnt, N + 1);
    build_kernel<<<eb, 256, 0, stream>>>(ei, E, cnt, bucket, ovf_src, ovf_dst, ovf_c);

    // layer 0
    gemm_kernel<4, true><<<gb, 256, 0, stream>>>(x, wf, wf + 16384, as0, ad0,
                                                 h, alpha_s, alpha_d, N);
    gather_kernel<4, true><<<wb, 128, 0, stream>>>(h, alpha_s, alpha_d, cnt,
                                                   bucket, ovf_src, ovf_dst,
                                                   ovf_c, b0, out, N);

    // layer 1
    gemm_kernel<4, true><<<gb, 256, 0, stream>>>(out, wf + 32768, wf + 49152,
                                                 as1, ad1, h, alpha_s, alpha_d, N);
    gather_kernel<4, true><<<wb, 128, 0, stream>>>(h, alpha_s, alpha_d, cnt,
                                                   bucket, ovf_src, ovf_dst,
                                                   ovf_c, b1, out, N);

    // layer 2 (H=1, fp32 h — final aggregation kept full precision)
    gemm_kernel<1, false><<<gb, 256, 0, stream>>>(out, wf + 65536, wf + 81920,
                                                  as2, ad2, h, alpha_s, alpha_d, N);
    gather_kernel<1, false><<<wb, 128, 0, stream>>>(h, alpha_s, alpha_d, cnt,
                                                    bucket, ovf_src, ovf_dst,
                                                    ovf_c, b2, out, N);
}